// Round 3
// baseline (1767.024 us; speedup 1.0000x reference)
//
#include <hip/hip_runtime.h>
#include <stdint.h>

// ---------------------------------------------------------------------------
// Qwen3.5-style layer on MI355X. fp32 in/out. Pre-router chain computed in
// split-bf16 (hi/lo) 3-pass MFMA => ~fp32 precision so the discrete top-2
// expert selection matches the fp32 reference. MoE GEMMs single bf16.
// ---------------------------------------------------------------------------

typedef __attribute__((ext_vector_type(8))) short short8;   // 8 bf16 = 16B
typedef __attribute__((ext_vector_type(4))) float floatx4;

#define DMODEL 1024
#define SEQ    1024
#define NHEAD  16
#define DK     64
#define DFF    2048
#define NEXP   8
#define MAXTILE 144

__device__ __forceinline__ float bf2f(unsigned short h){
  union{unsigned u;float f;}v; v.u=((unsigned)h)<<16; return v.f;
}
__device__ __forceinline__ unsigned short f2bf(float f){
  union{float f;unsigned u;}v; v.f=f;
  unsigned r=(v.u + 0x7FFFu + ((v.u>>16)&1u))>>16; return (unsigned short)r;
}
__device__ __forceinline__ void splitbf(float v, unsigned short& hi, unsigned short& lo){
  hi = f2bf(v); lo = f2bf(v - bf2f(hi));
}

__device__ __forceinline__ float block_sum(float v, float* red){
  for(int off=32;off;off>>=1) v += __shfl_down(v,off,64);
  int w = threadIdx.x>>6;
  __syncthreads();
  if((threadIdx.x&63)==0) red[w]=v;
  __syncthreads();
  return red[0]+red[1]+red[2]+red[3];
}

// ---- transpose fp32 -> split bf16 planes: dst[c][r] = src[r][c] ------------
__global__ __launch_bounds__(256) void k_transpose_f2(
    const float* __restrict__ src, unsigned short* __restrict__ dh,
    unsigned short* __restrict__ dl, long srs, long drs, long sbs, long dbs){
  __shared__ float t[32][33];
  src += (long)blockIdx.z*sbs; dh += (long)blockIdx.z*dbs; dl += (long)blockIdx.z*dbs;
  int c0 = blockIdx.x*32, r0 = blockIdx.y*32;
  int tx = threadIdx.x & 31, ty = threadIdx.x >> 5;
  for(int i=0;i<32;i+=8)
    t[ty+i][tx] = src[(long)(r0+ty+i)*srs + (c0+tx)];
  __syncthreads();
  for(int i=0;i<32;i+=8){
    unsigned short hi,lo; splitbf(t[tx][ty+i],hi,lo);
    long idx = (long)(c0+ty+i)*drs + (r0+tx);
    dh[idx]=hi; dl[idx]=lo;
  }
}

// ---- transpose fp32 -> single bf16 (MoE weights) ---------------------------
__global__ __launch_bounds__(256) void k_transpose_f(
    const float* __restrict__ src, unsigned short* __restrict__ dst,
    long srs, long drs, long sbs, long dbs){
  __shared__ float t[32][33];
  src += (long)blockIdx.z*sbs; dst += (long)blockIdx.z*dbs;
  int c0 = blockIdx.x*32, r0 = blockIdx.y*32;
  int tx = threadIdx.x & 31, ty = threadIdx.x >> 5;
  for(int i=0;i<32;i+=8)
    t[ty+i][tx] = src[(long)(r0+ty+i)*srs + (c0+tx)];
  __syncthreads();
  for(int i=0;i<32;i+=8)
    dst[(long)(c0+ty+i)*drs + (r0+tx)] = f2bf(t[tx][ty+i]);
}

// ---- transpose bf16 -> bf16 (vT planes) ------------------------------------
__global__ __launch_bounds__(256) void k_transpose_b(
    const unsigned short* __restrict__ src, unsigned short* __restrict__ dst,
    long srs, long drs, long sbs, long dbs){
  __shared__ unsigned short t[32][33];
  src += (long)blockIdx.z*sbs; dst += (long)blockIdx.z*dbs;
  int c0 = blockIdx.x*32, r0 = blockIdx.y*32;
  int tx = threadIdx.x & 31, ty = threadIdx.x >> 5;
  for(int i=0;i<32;i+=8)
    t[ty+i][tx] = src[(long)(r0+ty+i)*srs + (c0+tx)];
  __syncthreads();
  for(int i=0;i<32;i+=8)
    dst[(long)(c0+ty+i)*drs + (r0+tx)] = t[tx][ty+i];
}

// ---- LayerNorm 1: fp32 x -> split bf16 h1 ----------------------------------
__global__ __launch_bounds__(256) void k_ln1(
    const float* __restrict__ x, const float* __restrict__ g,
    const float* __restrict__ b, unsigned short* __restrict__ oh,
    unsigned short* __restrict__ ol){
  __shared__ float red[4];
  int t = blockIdx.x, tid = threadIdx.x;
  long base = (long)t*DMODEL + tid*4;
  floatx4 xv = *(const floatx4*)(x + base);
  float v[4] = {xv[0], xv[1], xv[2], xv[3]};
  float s = block_sum(v[0]+v[1]+v[2]+v[3], red);
  float mu = s * (1.f/DMODEL);
  float q=0.f;
  for(int i=0;i<4;i++){ float d=v[i]-mu; q+=d*d; }
  q = block_sum(q, red);
  float inv = rsqrtf(q*(1.f/DMODEL) + 1e-5f);
  for(int i=0;i<4;i++){
    int d = tid*4+i;
    unsigned short hi,lo; splitbf((v[i]-mu)*inv*g[d] + b[d], hi, lo);
    oh[base+i]=hi; ol[base+i]=lo;
  }
}

// ---- split GEMM: C[M,N] = (Ah+Al)[M,K] @ (Bh+Bl)[N,K]^T  -------------------
// SPLIT=1: write split bf16 planes Ch/Cl; SPLIT=0: write fp32 Cf.
template<int SPLIT>
__global__ __launch_bounds__(256) void k_gemm_ss(
    const unsigned short* __restrict__ Ah, const unsigned short* __restrict__ Al,
    const unsigned short* __restrict__ Bh, const unsigned short* __restrict__ Bl,
    unsigned short* __restrict__ Ch, unsigned short* __restrict__ Cl,
    float* __restrict__ Cf, int K, int lda, int ldb, int ldc){
  __shared__ unsigned short Ash[64][40], Asl[64][40];
  __shared__ unsigned short Bsh[64][40], Bsl[64][40];
  int m0 = blockIdx.y*64, n0 = blockIdx.x*64;
  int tid = threadIdx.x;
  int w = tid>>6, lane = tid&63, qm = lane&15, quad = lane>>4;
  int sr = tid>>2, sc = (tid&3)*8;
  floatx4 acc0={0,0,0,0},acc1={0,0,0,0},acc2={0,0,0,0},acc3={0,0,0,0};
  const unsigned short* Aph = Ah + (long)(m0+sr)*lda + sc;
  const unsigned short* Apl = Al + (long)(m0+sr)*lda + sc;
  const unsigned short* Bph = Bh + (long)(n0+sr)*ldb + sc;
  const unsigned short* Bpl = Bl + (long)(n0+sr)*ldb + sc;
  for(int k0=0;k0<K;k0+=32){
    short8 avh = *(const short8*)(Aph + k0);
    short8 avl = *(const short8*)(Apl + k0);
    short8 bvh = *(const short8*)(Bph + k0);
    short8 bvl = *(const short8*)(Bpl + k0);
    __syncthreads();
    *(short8*)(&Ash[sr][sc]) = avh;
    *(short8*)(&Asl[sr][sc]) = avl;
    *(short8*)(&Bsh[sr][sc]) = bvh;
    *(short8*)(&Bsl[sr][sc]) = bvl;
    __syncthreads();
    short8 ah = *(const short8*)(&Ash[w*16+qm][quad*8]);
    short8 al = *(const short8*)(&Asl[w*16+qm][quad*8]);
    short8 b0h = *(const short8*)(&Bsh[     qm][quad*8]);
    short8 b1h = *(const short8*)(&Bsh[16 + qm][quad*8]);
    short8 b2h = *(const short8*)(&Bsh[32 + qm][quad*8]);
    short8 b3h = *(const short8*)(&Bsh[48 + qm][quad*8]);
    short8 b0l = *(const short8*)(&Bsl[     qm][quad*8]);
    short8 b1l = *(const short8*)(&Bsl[16 + qm][quad*8]);
    short8 b2l = *(const short8*)(&Bsl[32 + qm][quad*8]);
    short8 b3l = *(const short8*)(&Bsl[48 + qm][quad*8]);
    acc0 = __builtin_amdgcn_mfma_f32_16x16x32_bf16(ah,b0h,acc0,0,0,0);
    acc1 = __builtin_amdgcn_mfma_f32_16x16x32_bf16(ah,b1h,acc1,0,0,0);
    acc2 = __builtin_amdgcn_mfma_f32_16x16x32_bf16(ah,b2h,acc2,0,0,0);
    acc3 = __builtin_amdgcn_mfma_f32_16x16x32_bf16(ah,b3h,acc3,0,0,0);
    acc0 = __builtin_amdgcn_mfma_f32_16x16x32_bf16(ah,b0l,acc0,0,0,0);
    acc1 = __builtin_amdgcn_mfma_f32_16x16x32_bf16(ah,b1l,acc1,0,0,0);
    acc2 = __builtin_amdgcn_mfma_f32_16x16x32_bf16(ah,b2l,acc2,0,0,0);
    acc3 = __builtin_amdgcn_mfma_f32_16x16x32_bf16(ah,b3l,acc3,0,0,0);
    acc0 = __builtin_amdgcn_mfma_f32_16x16x32_bf16(al,b0h,acc0,0,0,0);
    acc1 = __builtin_amdgcn_mfma_f32_16x16x32_bf16(al,b1h,acc1,0,0,0);
    acc2 = __builtin_amdgcn_mfma_f32_16x16x32_bf16(al,b2h,acc2,0,0,0);
    acc3 = __builtin_amdgcn_mfma_f32_16x16x32_bf16(al,b3h,acc3,0,0,0);
  }
  int row0 = m0 + w*16 + quad*4;
  for(int r=0;r<4;r++){
    long rb = (long)(row0+r)*ldc + n0;
    float v0=acc0[r], v1=acc1[r], v2=acc2[r], v3=acc3[r];
    if(SPLIT){
      unsigned short hi,lo;
      splitbf(v0,hi,lo); Ch[rb+     qm]=hi; Cl[rb+     qm]=lo;
      splitbf(v1,hi,lo); Ch[rb+16 + qm]=hi; Cl[rb+16 + qm]=lo;
      splitbf(v2,hi,lo); Ch[rb+32 + qm]=hi; Cl[rb+32 + qm]=lo;
      splitbf(v3,hi,lo); Ch[rb+48 + qm]=hi; Cl[rb+48 + qm]=lo;
    }else{
      Cf[rb+     qm]=v0; Cf[rb+16 + qm]=v1; Cf[rb+32 + qm]=v2; Cf[rb+48 + qm]=v3;
    }
  }
}

// ---- gate: softmax(h1 @ w_gate) (h1 split, wg fp32) ------------------------
__global__ __launch_bounds__(256) void k_gate(
    const unsigned short* __restrict__ hh, const unsigned short* __restrict__ hl,
    const float* __restrict__ wg, float* __restrict__ gates){
  int token = blockIdx.x*4 + (threadIdx.x>>6);
  int lane = threadIdx.x&63;
  long hb = (long)token*DMODEL + lane*16;
  const float* w = wg + lane*16*2;
  float s0=0.f, s1=0.f;
  for(int i=0;i<16;i++){
    float hv = bf2f(hh[hb+i]) + bf2f(hl[hb+i]);
    s0 += hv*w[2*i]; s1 += hv*w[2*i+1];
  }
  for(int off=32;off;off>>=1){ s0+=__shfl_down(s0,off,64); s1+=__shfl_down(s1,off,64); }
  if(lane==0){
    float m=fmaxf(s0,s1), e0=__expf(s0-m), e1=__expf(s1-m), inv=1.f/(e0+e1);
    gates[token*2]=e0*inv; gates[token*2+1]=e1*inv;
  }
}

// ---- flash attention, split precision: 16 queries/block, online softmax ----
__global__ __launch_bounds__(256) void k_attn_flash(
    const unsigned short* __restrict__ qh, const unsigned short* __restrict__ qlp,
    const unsigned short* __restrict__ vth, const unsigned short* __restrict__ vtl,
    const int* __restrict__ mask, unsigned short* __restrict__ dmh,
    unsigned short* __restrict__ dml){
  __shared__ unsigned short PWh[4][16][40], PWl[4][16][40];
  int bh = blockIdx.y, b = bh>>4, h = bh&15;
  int q0 = blockIdx.x*16;
  int tid=threadIdx.x, w=tid>>6, lane=tid&63, qm=lane&15, quad=lane>>4;
  long qrow = (long)(b*SEQ+q0+qm)*6144 + h*DK;
  short8 qh0 = *(const short8*)(qh +qrow+quad*8);
  short8 qh1 = *(const short8*)(qh +qrow+32+quad*8);
  short8 ql0 = *(const short8*)(qlp+qrow+quad*8);
  short8 ql1 = *(const short8*)(qlp+qrow+32+quad*8);
  float m[4], l[4]; floatx4 o={0,0,0,0};
  for(int r=0;r<4;r++){ m[r]=-3.0e38f; l[r]=0.f; }
  const unsigned short* vbh = vth + ((long)bh*DK + w*16 + qm)*SEQ;
  const unsigned short* vbl = vtl + ((long)bh*DK + w*16 + qm)*SEQ;
  for(int kt=0; kt<SEQ; kt+=32){
    floatx4 s0={0,0,0,0}, s1={0,0,0,0};
    {
      long kr = (long)(b*SEQ+kt+qm)*6144 + 1024 + h*DK;
      short8 kh0=*(const short8*)(qh +kr+quad*8), kh1=*(const short8*)(qh +kr+32+quad*8);
      short8 kl0=*(const short8*)(qlp+kr+quad*8), kl1=*(const short8*)(qlp+kr+32+quad*8);
      s0 = __builtin_amdgcn_mfma_f32_16x16x32_bf16(qh0,kh0,s0,0,0,0);
      s0 = __builtin_amdgcn_mfma_f32_16x16x32_bf16(qh1,kh1,s0,0,0,0);
      s0 = __builtin_amdgcn_mfma_f32_16x16x32_bf16(qh0,kl0,s0,0,0,0);
      s0 = __builtin_amdgcn_mfma_f32_16x16x32_bf16(qh1,kl1,s0,0,0,0);
      s0 = __builtin_amdgcn_mfma_f32_16x16x32_bf16(ql0,kh0,s0,0,0,0);
      s0 = __builtin_amdgcn_mfma_f32_16x16x32_bf16(ql1,kh1,s0,0,0,0);
      long kr1 = kr + 16L*6144;
      short8 jh0=*(const short8*)(qh +kr1+quad*8), jh1=*(const short8*)(qh +kr1+32+quad*8);
      short8 jl0=*(const short8*)(qlp+kr1+quad*8), jl1=*(const short8*)(qlp+kr1+32+quad*8);
      s1 = __builtin_amdgcn_mfma_f32_16x16x32_bf16(qh0,jh0,s1,0,0,0);
      s1 = __builtin_amdgcn_mfma_f32_16x16x32_bf16(qh1,jh1,s1,0,0,0);
      s1 = __builtin_amdgcn_mfma_f32_16x16x32_bf16(qh0,jl0,s1,0,0,0);
      s1 = __builtin_amdgcn_mfma_f32_16x16x32_bf16(qh1,jl1,s1,0,0,0);
      s1 = __builtin_amdgcn_mfma_f32_16x16x32_bf16(ql0,jh0,s1,0,0,0);
      s1 = __builtin_amdgcn_mfma_f32_16x16x32_bf16(ql1,jh1,s1,0,0,0);
    }
    const int* mb = mask + ((long)b*SEQ+q0)*SEQ + kt;
    for(int r=0;r<4;r++){
      int row = quad*4+r;
      float v0 = s0[r]*0.125f; if(mb[(long)row*SEQ+qm]==0)    v0=-1e9f;
      float v1 = s1[r]*0.125f; if(mb[(long)row*SEQ+16+qm]==0) v1=-1e9f;
      float tm = fmaxf(v0,v1);
      tm = fmaxf(tm, __shfl_xor(tm,1,16));
      tm = fmaxf(tm, __shfl_xor(tm,2,16));
      tm = fmaxf(tm, __shfl_xor(tm,4,16));
      tm = fmaxf(tm, __shfl_xor(tm,8,16));
      float nm = fmaxf(m[r], tm);
      float alpha = __expf(m[r]-nm);
      m[r]=nm;
      float p0=__expf(v0-nm), p1=__expf(v1-nm);
      float rs = p0+p1;
      rs += __shfl_xor(rs,1,16); rs += __shfl_xor(rs,2,16);
      rs += __shfl_xor(rs,4,16); rs += __shfl_xor(rs,8,16);
      l[r] = l[r]*alpha + rs;
      o[r] *= alpha;
      unsigned short hi,lo;
      splitbf(p0,hi,lo); PWh[w][row][qm]   =hi; PWl[w][row][qm]   =lo;
      splitbf(p1,hi,lo); PWh[w][row][16+qm]=hi; PWl[w][row][16+qm]=lo;
    }
    __syncthreads();
    short8 ph = *(const short8*)(&PWh[w][qm][quad*8]);
    short8 pl = *(const short8*)(&PWl[w][qm][quad*8]);
    short8 vh = *(const short8*)(vbh + kt + quad*8);
    short8 vl = *(const short8*)(vbl + kt + quad*8);
    o = __builtin_amdgcn_mfma_f32_16x16x32_bf16(ph,vh,o,0,0,0);
    o = __builtin_amdgcn_mfma_f32_16x16x32_bf16(ph,vl,o,0,0,0);
    o = __builtin_amdgcn_mfma_f32_16x16x32_bf16(pl,vh,o,0,0,0);
  }
  for(int r=0;r<4;r++){
    float val = o[r]/l[r];
    long idx = ((long)(b*SEQ+q0+quad*4+r))*DMODEL + h*DK + w*16 + qm;
    unsigned short hi,lo; splitbf(val,hi,lo);
    dmh[idx]=hi; dml[idx]=lo;
  }
}

// ---- delta: context & ksum per (b,h), fp32 from split inputs ---------------
__global__ __launch_bounds__(256) void k_delta_ctx(
    const unsigned short* __restrict__ qh, const unsigned short* __restrict__ qlp,
    float* __restrict__ ctx, float* __restrict__ ksum){
  int bh = blockIdx.x, b=bh>>4, h=bh&15;
  __shared__ unsigned short kdh[64][64], kdl[64][64], vdh[64][64], vdl[64][64];
  int tid = threadIdx.x;
  int i = tid>>2, jg = (tid&3)*16;
  float acc[16]; for(int k=0;k<16;k++) acc[k]=0.f;
  float ks = 0.f;
  int rr = tid>>2, cg = (tid&3)*16;
  for(int s0=0;s0<SEQ;s0+=64){
    __syncthreads();
    long base = (long)(b*SEQ + s0 + rr)*6144 + h*DK;
    *(short8*)(&kdh[rr][cg])   = *(const short8*)(qh  + base + 4096 + cg);
    *(short8*)(&kdh[rr][cg+8]) = *(const short8*)(qh  + base + 4096 + cg + 8);
    *(short8*)(&kdl[rr][cg])   = *(const short8*)(qlp + base + 4096 + cg);
    *(short8*)(&kdl[rr][cg+8]) = *(const short8*)(qlp + base + 4096 + cg + 8);
    *(short8*)(&vdh[rr][cg])   = *(const short8*)(qh  + base + 5120 + cg);
    *(short8*)(&vdh[rr][cg+8]) = *(const short8*)(qh  + base + 5120 + cg + 8);
    *(short8*)(&vdl[rr][cg])   = *(const short8*)(qlp + base + 5120 + cg);
    *(short8*)(&vdl[rr][cg+8]) = *(const short8*)(qlp + base + 5120 + cg + 8);
    __syncthreads();
    for(int s=0;s<64;s++){
      float kv = bf2f(kdh[s][i]) + bf2f(kdl[s][i]);
      if((tid&3)==0) ks += fmaxf(kv,0.f);
      for(int j=0;j<16;j++)
        acc[j] += kv * (bf2f(vdh[s][jg+j]) + bf2f(vdl[s][jg+j]));
    }
  }
  long cb = (long)bh*DK*DK;
  for(int j=0;j<16;j++) ctx[cb + (long)i*DK + jg + j] = acc[j];
  if((tid&3)==0) ksum[bh*DK + i] = ks;
}

// ---- delta: out = relu(qd)@ctx / z, split-bf16 output ----------------------
__global__ __launch_bounds__(256) void k_delta_out(
    const unsigned short* __restrict__ qh, const unsigned short* __restrict__ qlp,
    const float* __restrict__ ctx, const float* __restrict__ ksum,
    unsigned short* __restrict__ dlh, unsigned short* __restrict__ dll){
  int tok = blockIdx.x, b = tok>>10;
  int tid = threadIdx.x;
  __shared__ float ql[DMODEL];
  long sb = (long)tok*6144 + 3072;
  for(int c=tid;c<DMODEL;c+=256)
    ql[c] = fmaxf(bf2f(qh[sb+c]) + bf2f(qlp[sb+c]), 0.f);
  __syncthreads();
  int h = tid>>4, dg = (tid&15)*4;
  int bh = b*NHEAD + h;
  const float* C = ctx + (long)bh*DK*DK;
  const float* KS = ksum + bh*DK;
  float a0=0,a1=0,a2=0,a3=0,z=0;
  for(int d=0;d<DK;d++){
    float q = ql[h*DK + d];
    z += q * KS[d];
    const float* cr = C + d*DK + dg;
    a0 += q*cr[0]; a1 += q*cr[1]; a2 += q*cr[2]; a3 += q*cr[3];
  }
  float inv = 1.f/(z + 1e-6f);
  long db = (long)tok*DMODEL + h*DK + dg;
  unsigned short hi,lo;
  splitbf(a0*inv,hi,lo); dlh[db  ]=hi; dll[db  ]=lo;
  splitbf(a1*inv,hi,lo); dlh[db+1]=hi; dll[db+1]=lo;
  splitbf(a2*inv,hi,lo); dlh[db+2]=hi; dll[db+2]=lo;
  splitbf(a3*inv,hi,lo); dlh[db+3]=hi; dll[db+3]=lo;
}

// ---- fused: x1 = x+g0*dp+g1*dlp (fp32); h2=LN2(x1); router top2 ------------
__global__ __launch_bounds__(256) void k_comb_router(
    const float* __restrict__ x, const float* __restrict__ dp,
    const float* __restrict__ dlp, const float* __restrict__ gates,
    const float* __restrict__ g, const float* __restrict__ bb,
    const float* __restrict__ wr, unsigned short* __restrict__ h2b,
    float* __restrict__ topw, int* __restrict__ topi, int* __restrict__ counts){
  __shared__ float red[4];
  __shared__ float ered[4][8];
  int t = blockIdx.x, tid = threadIdx.x;
  float g0 = gates[t*2], g1 = gates[t*2+1];
  long base = (long)t*DMODEL + tid*4;
  floatx4 xv = *(const floatx4*)(x + base);
  float v[4];
  for(int i=0;i<4;i++) v[i] = xv[i] + g0*dp[base+i] + g1*dlp[base+i];
  float s = block_sum(v[0]+v[1]+v[2]+v[3], red);
  float mu = s*(1.f/DMODEL);
  float q=0.f; for(int i=0;i<4;i++){ float d=v[i]-mu; q+=d*d; }
  q = block_sum(q, red);
  float inv = rsqrtf(q*(1.f/DMODEL)+1e-5f);
  float a[8]; for(int e=0;e<8;e++) a[e]=0.f;
  for(int i=0;i<4;i++){
    int d = tid*4+i;
    float hv = (v[i]-mu)*inv*g[d] + bb[d];
    h2b[base+i] = f2bf(hv);
    const float* wrow = wr + (long)d*NEXP;
    for(int e=0;e<8;e++) a[e] += hv*wrow[e];
  }
  for(int off=32;off;off>>=1)
    for(int e=0;e<8;e++) a[e] += __shfl_down(a[e],off,64);
  int w = tid>>6;
  if((tid&63)==0) for(int e=0;e<8;e++) ered[w][e]=a[e];
  __syncthreads();
  if(tid==0){
    float lg[8];
    for(int e=0;e<8;e++) lg[e]=ered[0][e]+ered[1][e]+ered[2][e]+ered[3][e];
    int i0=0; for(int e=1;e<8;e++) if(lg[e]>lg[i0]) i0=e;
    int i1=-1; for(int e=0;e<8;e++){ if(e==i0) continue; if(i1<0||lg[e]>lg[i1]) i1=e; }
    float mm=fmaxf(lg[i0],lg[i1]), e0=__expf(lg[i0]-mm), e1=__expf(lg[i1]-mm), s2=1.f/(e0+e1);
    topw[t*2]=e0*s2; topw[t*2+1]=e1*s2;
    topi[t*2]=i0; topi[t*2+1]=i1;
    atomicAdd(&counts[i0],1); atomicAdd(&counts[i1],1);
  }
}

// ---- expert segment offsets + tile table -----------------------------------
__global__ void k_meta(const int* __restrict__ counts, int* offs, int* tE,
                       int* tR0, int* tR1, int* ntp, int* cursor){
  if(threadIdx.x==0){
    int o=0, nt=0;
    for(int e=0;e<NEXP;e++){
      offs[e]=o; cursor[e]=0;
      int n=counts[e];
      for(int t=0;t<(n+63)/64;t++){ tE[nt]=e; tR0[nt]=o+t*64; tR1[nt]=o+n; nt++; }
      o+=n;
    }
    offs[NEXP]=o; ntp[0]=nt;
  }
}

// ---- scatter tokens into expert-sorted slots -------------------------------
__global__ __launch_bounds__(256) void k_scatter(
    const int* __restrict__ topi, const int* __restrict__ offs,
    int* cursor, int* perm, int* slotof){
  int token = blockIdx.x*256 + threadIdx.x;
  for(int k=0;k<2;k++){
    int e = topi[token*2+k];
    int pos = atomicAdd(&cursor[e],1);
    int slot = offs[e]+pos;
    perm[slot]=token; slotof[token*2+k]=slot;
  }
}

// ---- MoE GEMM 1: H = gelu(gather(h2b) @ e_w1[e]) ---------------------------
__global__ __launch_bounds__(256) void k_moe1(
    const unsigned short* __restrict__ A, const unsigned short* __restrict__ BtA,
    unsigned short* __restrict__ H, const int* __restrict__ perm,
    const int* __restrict__ ntp, const int* __restrict__ tE,
    const int* __restrict__ tR0, const int* __restrict__ tR1){
  int bz = blockIdx.y;
  if(bz >= ntp[0]) return;
  int e = tE[bz], r0t = tR0[bz], r1t = tR1[bz];
  __shared__ int toks[64];
  __shared__ unsigned short As[64][40], Bs[64][40];
  int tid = threadIdx.x;
  if(tid<64){ int gg=r0t+tid; toks[tid] = (gg<r1t)? perm[gg] : -1; }
  __syncthreads();
  const unsigned short* Bt = BtA + (long)e*DFF*DMODEL;
  int n0 = blockIdx.x*64;
  int w=tid>>6, lane=tid&63, qm=lane&15, quad=lane>>4;
  int sr=tid>>2, sc=(tid&3)*8;
  int tok = toks[sr];
  floatx4 acc0={0,0,0,0},acc1={0,0,0,0},acc2={0,0,0,0},acc3={0,0,0,0};
  const short8 z8 = {0,0,0,0,0,0,0,0};
  const unsigned short* Bp = Bt + (long)(n0+sr)*DMODEL + sc;
  for(int k0=0;k0<DMODEL;k0+=32){
    short8 av = (tok>=0) ? *(const short8*)(A + (long)tok*DMODEL + k0 + sc) : z8;
    short8 bv = *(const short8*)(Bp + k0);
    __syncthreads();
    *(short8*)(&As[sr][sc]) = av;
    *(short8*)(&Bs[sr][sc]) = bv;
    __syncthreads();
    short8 a  = *(const short8*)(&As[w*16+qm][quad*8]);
    short8 b0 = *(const short8*)(&Bs[     qm][quad*8]);
    short8 b1 = *(const short8*)(&Bs[16 + qm][quad*8]);
    short8 b2 = *(const short8*)(&Bs[32 + qm][quad*8]);
    short8 b3 = *(const short8*)(&Bs[48 + qm][quad*8]);
    acc0 = __builtin_amdgcn_mfma_f32_16x16x32_bf16(a,b0,acc0,0,0,0);
    acc1 = __builtin_amdgcn_mfma_f32_16x16x32_bf16(a,b1,acc1,0,0,0);
    acc2 = __builtin_amdgcn_mfma_f32_16x16x32_bf16(a,b2,acc2,0,0,0);
    acc3 = __builtin_amdgcn_mfma_f32_16x16x32_bf16(a,b3,acc3,0,0,0);
  }
  for(int r=0;r<4;r++){
    int gr = r0t + w*16 + quad*4 + r;
    if(gr < r1t){
      long rb = (long)gr*DFF + n0;
      float xx;
      xx=acc0[r]; H[rb+     qm]=f2bf(0.5f*xx*(1.f+erff(xx*0.70710678f)));
      xx=acc1[r]; H[rb+16 + qm]=f2bf(0.5f*xx*(1.f+erff(xx*0.70710678f)));
      xx=acc2[r]; H[rb+32 + qm]=f2bf(0.5f*xx*(1.f+erff(xx*0.70710678f)));
      xx=acc3[r]; H[rb+48 + qm]=f2bf(0.5f*xx*(1.f+erff(xx*0.70710678f)));
    }
  }
}

// ---- MoE GEMM 2: Y = H @ e_w2[e] -------------------------------------------
__global__ __launch_bounds__(256) void k_moe2(
    const unsigned short* __restrict__ H, const unsigned short* __restrict__ BtA,
    unsigned short* __restrict__ Y, const int* __restrict__ ntp,
    const int* __restrict__ tE, const int* __restrict__ tR0,
    const int* __restrict__ tR1){
  int bz = blockIdx.y;
  if(bz >= ntp[0]) return;
  int e = tE[bz], r0t = tR0[bz], r1t = tR1[bz];
  __shared__ unsigned short As[64][40], Bs[64][40];
  int tid = threadIdx.x;
  const unsigned short* Bt = BtA + (long)e*DMODEL*DFF;
  int n0 = blockIdx.x*64;
  int w=tid>>6, lane=tid&63, qm=lane&15, quad=lane>>4;
  int sr=tid>>2, sc=(tid&3)*8;
  int grow = r0t + sr;
  bool vrow = grow < r1t;
  floatx4 acc0={0,0,0,0},acc1={0,0,0,0},acc2={0,0,0,0},acc3={0,0,0,0};
  const short8 z8 = {0,0,0,0,0,0,0,0};
  const unsigned short* Ap = H + (long)grow*DFF + sc;
  const unsigned short* Bp = Bt + (long)(n0+sr)*DFF + sc;
  for(int k0=0;k0<DFF;k0+=32){
    short8 av = vrow ? *(const short8*)(Ap + k0) : z8;
    short8 bv = *(const short8*)(Bp + k0);
    __syncthreads();
    *(short8*)(&As[sr][sc]) = av;
    *(short8*)(&Bs[sr][sc]) = bv;
    __syncthreads();
    short8 a  = *(const short8*)(&As[w*16+qm][quad*8]);
    short8 b0 = *(const short8*)(&Bs[     qm][quad*8]);
    short8 b1 = *(const short8*)(&Bs[16 + qm][quad*8]);
    short8 b2 = *(const short8*)(&Bs[32 + qm][quad*8]);
    short8 b3 = *(const short8*)(&Bs[48 + qm][quad*8]);
    acc0 = __builtin_amdgcn_mfma_f32_16x16x32_bf16(a,b0,acc0,0,0,0);
    acc1 = __builtin_amdgcn_mfma_f32_16x16x32_bf16(a,b1,acc1,0,0,0);
    acc2 = __builtin_amdgcn_mfma_f32_16x16x32_bf16(a,b2,acc2,0,0,0);
    acc3 = __builtin_amdgcn_mfma_f32_16x16x32_bf16(a,b3,acc3,0,0,0);
  }
  for(int r=0;r<4;r++){
    int gr = r0t + w*16 + quad*4 + r;
    if(gr < r1t){
      long rb = (long)gr*DMODEL + n0;
      Y[rb+     qm]=f2bf(acc0[r]);
      Y[rb+16 + qm]=f2bf(acc1[r]);
      Y[rb+32 + qm]=f2bf(acc2[r]);
      Y[rb+48 + qm]=f2bf(acc3[r]);
    }
  }
}

// ---- final: out = x + g0*dp + g1*dlp + w0*Y[s0] + w1*Y[s1] (fp32) ----------
__global__ __launch_bounds__(256) void k_final(
    const float* __restrict__ x, const float* __restrict__ dp,
    const float* __restrict__ dlp, const float* __restrict__ gates,
    const unsigned short* __restrict__ Y, const int* __restrict__ slotof,
    const float* __restrict__ topw, float* __restrict__ out){
  int t = blockIdx.x, tid = threadIdx.x;
  int s0 = slotof[t*2], s1 = slotof[t*2+1];
  float w0 = topw[t*2], w1 = topw[t*2+1];
  float g0 = gates[t*2], g1 = gates[t*2+1];
  long base = (long)t*DMODEL + tid*4;
  const unsigned short* y0 = Y + (long)s0*DMODEL + tid*4;
  const unsigned short* y1 = Y + (long)s1*DMODEL + tid*4;
  floatx4 xv = *(const floatx4*)(x + base);
  for(int i=0;i<4;i++)
    out[base+i] = xv[i] + g0*dp[base+i] + g1*dlp[base+i]
                        + w0*bf2f(y0[i]) + w1*bf2f(y1[i]);
}

// ===========================================================================
extern "C" void kernel_launch(void* const* d_in, const int* in_sizes, int n_in,
                              void* d_out, int out_size, void* d_ws, size_t ws_size,
                              hipStream_t stream){
  const float* x    = (const float*)d_in[0];
  const int*   mask = (const int*)d_in[1];
  const float* ln1g = (const float*)d_in[2];
  const float* ln1b = (const float*)d_in[3];
  const float* wq   = (const float*)d_in[4];
  const float* wk   = (const float*)d_in[5];
  const float* wv   = (const float*)d_in[6];
  const float* wo   = (const float*)d_in[7];
  const float* wqd  = (const float*)d_in[8];
  const float* wkd  = (const float*)d_in[9];
  const float* wvd  = (const float*)d_in[10];
  const float* wod  = (const float*)d_in[11];
  const float* wg   = (const float*)d_in[12];
  const float* ln2g = (const float*)d_in[13];
  const float* ln2b = (const float*)d_in[14];
  const float* wr   = (const float*)d_in[15];
  const float* ew1  = (const float*)d_in[16];
  const float* ew2  = (const float*)d_in[17];
  float* out = (float*)d_out;

  char* p = (char*)d_ws;
  auto alloc = [&](size_t b)->char*{ char* r=p; p += (b + 255) & ~(size_t)255; return r; };
  unsigned short* WtAllh = (unsigned short*)alloc(6144L*1024*2);
  unsigned short* WtAlll = (unsigned short*)alloc(6144L*1024*2);
  unsigned short* WoTh   = (unsigned short*)alloc(1024L*1024*2);
  unsigned short* WoTl   = (unsigned short*)alloc(1024L*1024*2);
  unsigned short* WodTh  = (unsigned short*)alloc(1024L*1024*2);
  unsigned short* WodTl  = (unsigned short*)alloc(1024L*1024*2);
  unsigned short* eW1T   = (unsigned short*)alloc(8L*2048*1024*2);
  unsigned short* eW2T   = (unsigned short*)alloc(8L*1024*2048*2);
  unsigned short* h1h    = (unsigned short*)alloc(4096L*1024*2);  // later vTh
  unsigned short* h1l    = (unsigned short*)alloc(4096L*1024*2);  // later vTl
  unsigned short* qkvh   = (unsigned short*)alloc(4096L*6144*2);  // later dproj+dlproj (fp32)
  unsigned short* qkvl   = (unsigned short*)alloc(4096L*6144*2);  // later H
  unsigned short* dmh    = (unsigned short*)alloc(4096L*1024*2);  // later Y (dmh..dml)
  unsigned short* dml    = (unsigned short*)alloc(4096L*1024*2);
  unsigned short* dlh    = (unsigned short*)alloc(4096L*1024*2);
  unsigned short* dll    = (unsigned short*)alloc(4096L*1024*2);
  float* ctx   = (float*)alloc(64L*64*64*4);
  float* ksum  = (float*)alloc(64L*64*4);
  float* gates = (float*)alloc(4096L*2*4);
  unsigned short* h2b = (unsigned short*)alloc(4096L*1024*2);
  float* topw = (float*)alloc(4096L*2*4);
  int* topi   = (int*)alloc(4096L*2*4);
  int* slotof = (int*)alloc(4096L*2*4);
  int* perm   = (int*)alloc(8192L*4);
  int* counts = (int*)alloc(64*4);
  int* cursor = (int*)alloc(64*4);
  int* offs   = (int*)alloc(64*4);
  int* ntp    = (int*)alloc(64*4);
  int* tE     = (int*)alloc(MAXTILE*4);
  int* tR0    = (int*)alloc(MAXTILE*4);
  int* tR1    = (int*)alloc(MAXTILE*4);
  if ((size_t)(p - (char*)d_ws) > ws_size) return;  // ws too small -> absmax==ref max

  unsigned short* vTh = h1h;                    // after h1 consumed (qkv gemm + gate)
  unsigned short* vTl = h1l;
  float* dproj  = (float*)qkvh;                 // after qkv consumed (attn+delta)
  float* dlproj = (float*)(qkvh + 8388608);     // second 16.8MB of qkvh region
  unsigned short* H = qkvl;                     // after qkv consumed
  unsigned short* Y = dmh;                      // spans dmh+dml (16.8MB)

  dim3 tb(256);
  // weight transposes: attention weights split, MoE weights single bf16
  k_transpose_f2<<<dim3(32,32,1),tb,0,stream>>>(wq,  WtAllh+0L*1048576, WtAlll+0L*1048576, 1024,1024, 0,0);
  k_transpose_f2<<<dim3(32,32,1),tb,0,stream>>>(wk,  WtAllh+1L*1048576, WtAlll+1L*1048576, 1024,1024, 0,0);
  k_transpose_f2<<<dim3(32,32,1),tb,0,stream>>>(wv,  WtAllh+2L*1048576, WtAlll+2L*1048576, 1024,1024, 0,0);
  k_transpose_f2<<<dim3(32,32,1),tb,0,stream>>>(wqd, WtAllh+3L*1048576, WtAlll+3L*1048576, 1024,1024, 0,0);
  k_transpose_f2<<<dim3(32,32,1),tb,0,stream>>>(wkd, WtAllh+4L*1048576, WtAlll+4L*1048576, 1024,1024, 0,0);
  k_transpose_f2<<<dim3(32,32,1),tb,0,stream>>>(wvd, WtAllh+5L*1048576, WtAlll+5L*1048576, 1024,1024, 0,0);
  k_transpose_f2<<<dim3(32,32,1),tb,0,stream>>>(wo,  WoTh,  WoTl,  1024,1024, 0,0);
  k_transpose_f2<<<dim3(32,32,1),tb,0,stream>>>(wod, WodTh, WodTl, 1024,1024, 0,0);
  k_transpose_f<<<dim3(64,32,8),tb,0,stream>>>(ew1, eW1T, 2048,1024, 1024L*2048, 2048L*1024);
  k_transpose_f<<<dim3(32,64,8),tb,0,stream>>>(ew2, eW2T, 1024,2048, 2048L*1024, 1024L*2048);
  // LN1 -> h1 split
  k_ln1<<<4096,tb,0,stream>>>(x, ln1g, ln1b, h1h, h1l);
  // qkv: all 6 projections, split in/out
  k_gemm_ss<1><<<dim3(96,64),tb,0,stream>>>(h1h,h1l, WtAllh,WtAlll, qkvh,qkvl,nullptr,
                                            1024, 1024, 1024, 6144);
  // gate (fp32 path)
  k_gate<<<1024,tb,0,stream>>>(h1h, h1l, wg, gates);
  // vT planes per (b,h): [dk][s]
  for(int b=0;b<4;b++){
    k_transpose_b<<<dim3(2,32,16),tb,0,stream>>>(qkvh + (long)b*1024*6144 + 2048,
        vTh + (long)b*16*65536, 6144,1024, 64, 65536);
    k_transpose_b<<<dim3(2,32,16),tb,0,stream>>>(qkvl + (long)b*1024*6144 + 2048,
        vTl + (long)b*16*65536, 6144,1024, 64, 65536);
  }
  // flash attention (split precision)
  k_attn_flash<<<dim3(64,64),tb,0,stream>>>(qkvh, qkvl, vTh, vTl, mask, dmh, dml);
  // delta branch
  k_delta_ctx<<<64,tb,0,stream>>>(qkvh, qkvl, ctx, ksum);
  k_delta_out<<<4096,tb,0,stream>>>(qkvh, qkvl, ctx, ksum, dlh, dll);
  // output projections -> fp32
  k_gemm_ss<0><<<dim3(16,64),tb,0,stream>>>(dmh,dml, WoTh,WoTl,  nullptr,nullptr,dproj,
                                            1024, 1024, 1024, 1024);
  k_gemm_ss<0><<<dim3(16,64),tb,0,stream>>>(dlh,dll, WodTh,WodTl, nullptr,nullptr,dlproj,
                                            1024, 1024, 1024, 1024);
  // residual + gate-mix + LN2 + router (all fp32)
  hipMemsetAsync(counts, 0, NEXP*sizeof(int), stream);
  k_comb_router<<<4096,tb,0,stream>>>(x, dproj, dlproj, gates, ln2g, ln2b, wr,
                                      h2b, topw, topi, counts);
  k_meta<<<1,64,0,stream>>>(counts, offs, tE, tR0, tR1, ntp, cursor);
  k_scatter<<<16,tb,0,stream>>>(topi, offs, cursor, perm, slotof);
  // expert GEMMs
  k_moe1<<<dim3(32,136),tb,0,stream>>>(h2b, eW1T, H, perm, ntp, tE, tR0, tR1);
  k_moe2<<<dim3(16,136),tb,0,stream>>>(H, eW2T, Y, ntp, tE, tR0, tR1);
  // final residual combine
  k_final<<<4096,tb,0,stream>>>(x, dproj, dlproj, gates, Y, slotof, topw, out);
}

// Round 4
// 1400.481 us; speedup vs baseline: 1.2617x; 1.2617x over previous
//
#include <hip/hip_runtime.h>
#include <stdint.h>

// ---------------------------------------------------------------------------
// Qwen3.5-style layer on MI355X. fp32 in/out. Pre-router chain computed in
// split-bf16 (hi/lo) 3-pass MFMA => ~fp32 precision so the discrete top-2
// expert selection matches the fp32 reference. MoE GEMMs single bf16.
// R4: attention rewritten — 64q x 64k tiles, wave-autonomous (no block
// barrier in K-loop), bit-packed mask, merged vT transpose.
// ---------------------------------------------------------------------------

typedef __attribute__((ext_vector_type(8))) short short8;   // 8 bf16 = 16B
typedef __attribute__((ext_vector_type(4))) float floatx4;

#define DMODEL 1024
#define SEQ    1024
#define NHEAD  16
#define DK     64
#define DFF    2048
#define NEXP   8
#define MAXTILE 144

__device__ __forceinline__ float bf2f(unsigned short h){
  union{unsigned u;float f;}v; v.u=((unsigned)h)<<16; return v.f;
}
__device__ __forceinline__ unsigned short f2bf(float f){
  union{float f;unsigned u;}v; v.f=f;
  unsigned r=(v.u + 0x7FFFu + ((v.u>>16)&1u))>>16; return (unsigned short)r;
}
__device__ __forceinline__ void splitbf(float v, unsigned short& hi, unsigned short& lo){
  hi = f2bf(v); lo = f2bf(v - bf2f(hi));
}

__device__ __forceinline__ float block_sum(float v, float* red){
  for(int off=32;off;off>>=1) v += __shfl_down(v,off,64);
  int w = threadIdx.x>>6;
  __syncthreads();
  if((threadIdx.x&63)==0) red[w]=v;
  __syncthreads();
  return red[0]+red[1]+red[2]+red[3];
}

// ---- pack mask to bits: one wave per 64-int chunk --------------------------
__global__ __launch_bounds__(256) void k_maskpack(
    const int* __restrict__ mask, unsigned long long* __restrict__ mp){
  int gw = blockIdx.x*4 + (threadIdx.x>>6);
  int lane = threadIdx.x&63;
  unsigned long long bm = __ballot(mask[(long)gw*64 + lane] != 0);
  if(lane==0) mp[gw]=bm;
}

// ---- transpose fp32 -> split bf16 planes: dst[c][r] = src[r][c] ------------
__global__ __launch_bounds__(256) void k_transpose_f2(
    const float* __restrict__ src, unsigned short* __restrict__ dh,
    unsigned short* __restrict__ dl, long srs, long drs, long sbs, long dbs){
  __shared__ float t[32][33];
  src += (long)blockIdx.z*sbs; dh += (long)blockIdx.z*dbs; dl += (long)blockIdx.z*dbs;
  int c0 = blockIdx.x*32, r0 = blockIdx.y*32;
  int tx = threadIdx.x & 31, ty = threadIdx.x >> 5;
  for(int i=0;i<32;i+=8)
    t[ty+i][tx] = src[(long)(r0+ty+i)*srs + (c0+tx)];
  __syncthreads();
  for(int i=0;i<32;i+=8){
    unsigned short hi,lo; splitbf(t[tx][ty+i],hi,lo);
    long idx = (long)(c0+ty+i)*drs + (r0+tx);
    dh[idx]=hi; dl[idx]=lo;
  }
}

// ---- transpose fp32 -> single bf16 (MoE weights) ---------------------------
__global__ __launch_bounds__(256) void k_transpose_f(
    const float* __restrict__ src, unsigned short* __restrict__ dst,
    long srs, long drs, long sbs, long dbs){
  __shared__ float t[32][33];
  src += (long)blockIdx.z*sbs; dst += (long)blockIdx.z*dbs;
  int c0 = blockIdx.x*32, r0 = blockIdx.y*32;
  int tx = threadIdx.x & 31, ty = threadIdx.x >> 5;
  for(int i=0;i<32;i+=8)
    t[ty+i][tx] = src[(long)(r0+ty+i)*srs + (c0+tx)];
  __syncthreads();
  for(int i=0;i<32;i+=8)
    dst[(long)(c0+ty+i)*drs + (r0+tx)] = f2bf(t[tx][ty+i]);
}

// ---- vT: both planes, all (b,h) in one launch. dst[bh][dk][s] --------------
__global__ __launch_bounds__(256) void k_vt(
    const unsigned short* __restrict__ qh, const unsigned short* __restrict__ ql,
    unsigned short* __restrict__ vth, unsigned short* __restrict__ vtl){
  __shared__ unsigned short th[32][33], tl[32][33];
  int z = blockIdx.z, b = z>>4, h = z&15;
  int s0 = blockIdx.x*32, d0 = blockIdx.y*32;
  int tx = threadIdx.x & 31, ty = threadIdx.x >> 5;
  for(int i=0;i<32;i+=8){
    long src = (long)(b*SEQ + s0+ty+i)*6144 + 2048 + h*DK + d0+tx;
    th[ty+i][tx] = qh[src]; tl[ty+i][tx] = ql[src];
  }
  __syncthreads();
  for(int i=0;i<32;i+=8){
    long dst = ((long)z*DK + d0+ty+i)*SEQ + s0+tx;
    vth[dst] = th[tx][ty+i]; vtl[dst] = tl[tx][ty+i];
  }
}

// ---- LayerNorm 1: fp32 x -> split bf16 h1 ----------------------------------
__global__ __launch_bounds__(256) void k_ln1(
    const float* __restrict__ x, const float* __restrict__ g,
    const float* __restrict__ b, unsigned short* __restrict__ oh,
    unsigned short* __restrict__ ol){
  __shared__ float red[4];
  int t = blockIdx.x, tid = threadIdx.x;
  long base = (long)t*DMODEL + tid*4;
  floatx4 xv = *(const floatx4*)(x + base);
  float v[4] = {xv[0], xv[1], xv[2], xv[3]};
  float s = block_sum(v[0]+v[1]+v[2]+v[3], red);
  float mu = s * (1.f/DMODEL);
  float q=0.f;
  for(int i=0;i<4;i++){ float d=v[i]-mu; q+=d*d; }
  q = block_sum(q, red);
  float inv = rsqrtf(q*(1.f/DMODEL) + 1e-5f);
  for(int i=0;i<4;i++){
    int d = tid*4+i;
    unsigned short hi,lo; splitbf((v[i]-mu)*inv*g[d] + b[d], hi, lo);
    oh[base+i]=hi; ol[base+i]=lo;
  }
}

// ---- split GEMM: C[M,N] = (Ah+Al)[M,K] @ (Bh+Bl)[N,K]^T  -------------------
template<int SPLIT>
__global__ __launch_bounds__(256) void k_gemm_ss(
    const unsigned short* __restrict__ Ah, const unsigned short* __restrict__ Al,
    const unsigned short* __restrict__ Bh, const unsigned short* __restrict__ Bl,
    unsigned short* __restrict__ Ch, unsigned short* __restrict__ Cl,
    float* __restrict__ Cf, int K, int lda, int ldb, int ldc){
  __shared__ unsigned short Ash[64][40], Asl[64][40];
  __shared__ unsigned short Bsh[64][40], Bsl[64][40];
  int m0 = blockIdx.y*64, n0 = blockIdx.x*64;
  int tid = threadIdx.x;
  int w = tid>>6, lane = tid&63, qm = lane&15, quad = lane>>4;
  int sr = tid>>2, sc = (tid&3)*8;
  floatx4 acc0={0,0,0,0},acc1={0,0,0,0},acc2={0,0,0,0},acc3={0,0,0,0};
  const unsigned short* Aph = Ah + (long)(m0+sr)*lda + sc;
  const unsigned short* Apl = Al + (long)(m0+sr)*lda + sc;
  const unsigned short* Bph = Bh + (long)(n0+sr)*ldb + sc;
  const unsigned short* Bpl = Bl + (long)(n0+sr)*ldb + sc;
  for(int k0=0;k0<K;k0+=32){
    short8 avh = *(const short8*)(Aph + k0);
    short8 avl = *(const short8*)(Apl + k0);
    short8 bvh = *(const short8*)(Bph + k0);
    short8 bvl = *(const short8*)(Bpl + k0);
    __syncthreads();
    *(short8*)(&Ash[sr][sc]) = avh;
    *(short8*)(&Asl[sr][sc]) = avl;
    *(short8*)(&Bsh[sr][sc]) = bvh;
    *(short8*)(&Bsl[sr][sc]) = bvl;
    __syncthreads();
    short8 ah = *(const short8*)(&Ash[w*16+qm][quad*8]);
    short8 al = *(const short8*)(&Asl[w*16+qm][quad*8]);
    short8 b0h = *(const short8*)(&Bsh[     qm][quad*8]);
    short8 b1h = *(const short8*)(&Bsh[16 + qm][quad*8]);
    short8 b2h = *(const short8*)(&Bsh[32 + qm][quad*8]);
    short8 b3h = *(const short8*)(&Bsh[48 + qm][quad*8]);
    short8 b0l = *(const short8*)(&Bsl[     qm][quad*8]);
    short8 b1l = *(const short8*)(&Bsl[16 + qm][quad*8]);
    short8 b2l = *(const short8*)(&Bsl[32 + qm][quad*8]);
    short8 b3l = *(const short8*)(&Bsl[48 + qm][quad*8]);
    acc0 = __builtin_amdgcn_mfma_f32_16x16x32_bf16(ah,b0h,acc0,0,0,0);
    acc1 = __builtin_amdgcn_mfma_f32_16x16x32_bf16(ah,b1h,acc1,0,0,0);
    acc2 = __builtin_amdgcn_mfma_f32_16x16x32_bf16(ah,b2h,acc2,0,0,0);
    acc3 = __builtin_amdgcn_mfma_f32_16x16x32_bf16(ah,b3h,acc3,0,0,0);
    acc0 = __builtin_amdgcn_mfma_f32_16x16x32_bf16(ah,b0l,acc0,0,0,0);
    acc1 = __builtin_amdgcn_mfma_f32_16x16x32_bf16(ah,b1l,acc1,0,0,0);
    acc2 = __builtin_amdgcn_mfma_f32_16x16x32_bf16(ah,b2l,acc2,0,0,0);
    acc3 = __builtin_amdgcn_mfma_f32_16x16x32_bf16(ah,b3l,acc3,0,0,0);
    acc0 = __builtin_amdgcn_mfma_f32_16x16x32_bf16(al,b0h,acc0,0,0,0);
    acc1 = __builtin_amdgcn_mfma_f32_16x16x32_bf16(al,b1h,acc1,0,0,0);
    acc2 = __builtin_amdgcn_mfma_f32_16x16x32_bf16(al,b2h,acc2,0,0,0);
    acc3 = __builtin_amdgcn_mfma_f32_16x16x32_bf16(al,b3h,acc3,0,0,0);
  }
  int row0 = m0 + w*16 + quad*4;
  for(int r=0;r<4;r++){
    long rb = (long)(row0+r)*ldc + n0;
    float v0=acc0[r], v1=acc1[r], v2=acc2[r], v3=acc3[r];
    if(SPLIT){
      unsigned short hi,lo;
      splitbf(v0,hi,lo); Ch[rb+     qm]=hi; Cl[rb+     qm]=lo;
      splitbf(v1,hi,lo); Ch[rb+16 + qm]=hi; Cl[rb+16 + qm]=lo;
      splitbf(v2,hi,lo); Ch[rb+32 + qm]=hi; Cl[rb+32 + qm]=lo;
      splitbf(v3,hi,lo); Ch[rb+48 + qm]=hi; Cl[rb+48 + qm]=lo;
    }else{
      Cf[rb+     qm]=v0; Cf[rb+16 + qm]=v1; Cf[rb+32 + qm]=v2; Cf[rb+48 + qm]=v3;
    }
  }
}

// ---- gate: softmax(h1 @ w_gate) (h1 split, wg fp32) ------------------------
__global__ __launch_bounds__(256) void k_gate(
    const unsigned short* __restrict__ hh, const unsigned short* __restrict__ hl,
    const float* __restrict__ wg, float* __restrict__ gates){
  int token = blockIdx.x*4 + (threadIdx.x>>6);
  int lane = threadIdx.x&63;
  long hb = (long)token*DMODEL + lane*16;
  const float* w = wg + lane*16*2;
  float s0=0.f, s1=0.f;
  for(int i=0;i<16;i++){
    float hv = bf2f(hh[hb+i]) + bf2f(hl[hb+i]);
    s0 += hv*w[2*i]; s1 += hv*w[2*i+1];
  }
  for(int off=32;off;off>>=1){ s0+=__shfl_down(s0,off,64); s1+=__shfl_down(s1,off,64); }
  if(lane==0){
    float m=fmaxf(s0,s1), e0=__expf(s0-m), e1=__expf(s1-m), inv=1.f/(e0+e1);
    gates[token*2]=e0*inv; gates[token*2+1]=e1*inv;
  }
}

// ---- flash attention v2: 64q x 64k tiles, wave-autonomous ------------------
__global__ __launch_bounds__(256) void k_attn_flash2(
    const unsigned short* __restrict__ qh, const unsigned short* __restrict__ qlp,
    const unsigned short* __restrict__ vth, const unsigned short* __restrict__ vtl,
    const unsigned long long* __restrict__ mp, unsigned short* __restrict__ dmh,
    unsigned short* __restrict__ dml){
  __shared__ unsigned short PWh[4][16][72], PWl[4][16][72];
  int bh = blockIdx.y, b = bh>>4, h = bh&15;
  int tid = threadIdx.x, w = tid>>6, qm = tid&15, quad = (tid>>4)&3;
  int q0 = blockIdx.x*64 + w*16;
  long qrow = (long)(b*SEQ+q0+qm)*6144 + h*DK;
  short8 a_qh0 = *(const short8*)(qh +qrow+quad*8);
  short8 a_qh1 = *(const short8*)(qh +qrow+32+quad*8);
  short8 a_ql0 = *(const short8*)(qlp+qrow+quad*8);
  short8 a_ql1 = *(const short8*)(qlp+qrow+32+quad*8);
  float m[4], l[4];
  floatx4 o0={0,0,0,0}, o1={0,0,0,0}, o2={0,0,0,0}, o3={0,0,0,0};
  #pragma unroll
  for(int r=0;r<4;r++){ m[r]=-3.0e38f; l[r]=0.f; }
  const unsigned long long* mrow = mp + ((long)b*SEQ + q0 + quad*4)*16;
  const unsigned short* vbase_h = vth + (long)bh*DK*SEQ;
  const unsigned short* vbase_l = vtl + (long)bh*DK*SEQ;
  for(int kt=0; kt<SEQ; kt+=64){
    int wd = kt>>6;
    unsigned long long mws[4] = {mrow[wd], mrow[16+wd], mrow[32+wd], mrow[48+wd]};
    floatx4 s[4];
    #pragma unroll
    for(int st=0;st<4;st++){
      long kr = (long)(b*SEQ + kt + st*16 + qm)*6144 + 1024 + h*DK;
      short8 kh0 = *(const short8*)(qh +kr+quad*8);
      short8 kh1 = *(const short8*)(qh +kr+32+quad*8);
      short8 kl0 = *(const short8*)(qlp+kr+quad*8);
      short8 kl1 = *(const short8*)(qlp+kr+32+quad*8);
      floatx4 acc = {0,0,0,0};
      acc = __builtin_amdgcn_mfma_f32_16x16x32_bf16(a_qh0,kh0,acc,0,0,0);
      acc = __builtin_amdgcn_mfma_f32_16x16x32_bf16(a_qh1,kh1,acc,0,0,0);
      acc = __builtin_amdgcn_mfma_f32_16x16x32_bf16(a_qh0,kl0,acc,0,0,0);
      acc = __builtin_amdgcn_mfma_f32_16x16x32_bf16(a_qh1,kl1,acc,0,0,0);
      acc = __builtin_amdgcn_mfma_f32_16x16x32_bf16(a_ql0,kh0,acc,0,0,0);
      acc = __builtin_amdgcn_mfma_f32_16x16x32_bf16(a_ql1,kh1,acc,0,0,0);
      s[st] = acc;
    }
    #pragma unroll
    for(int r=0;r<4;r++){
      float v0 = ((mws[r]>>(   qm))&1) ? s[0][r]*0.125f : -1e9f;
      float v1 = ((mws[r]>>(16+qm))&1) ? s[1][r]*0.125f : -1e9f;
      float v2 = ((mws[r]>>(32+qm))&1) ? s[2][r]*0.125f : -1e9f;
      float v3 = ((mws[r]>>(48+qm))&1) ? s[3][r]*0.125f : -1e9f;
      float tm = fmaxf(fmaxf(v0,v1), fmaxf(v2,v3));
      tm = fmaxf(tm, __shfl_xor(tm,1,16));
      tm = fmaxf(tm, __shfl_xor(tm,2,16));
      tm = fmaxf(tm, __shfl_xor(tm,4,16));
      tm = fmaxf(tm, __shfl_xor(tm,8,16));
      float nm = fmaxf(m[r], tm);
      float al = __expf(m[r]-nm);
      m[r] = nm;
      float p0=__expf(v0-nm), p1=__expf(v1-nm), p2=__expf(v2-nm), p3=__expf(v3-nm);
      float rs = p0+p1+p2+p3;
      rs += __shfl_xor(rs,1,16); rs += __shfl_xor(rs,2,16);
      rs += __shfl_xor(rs,4,16); rs += __shfl_xor(rs,8,16);
      l[r] = l[r]*al + rs;
      o0[r]*=al; o1[r]*=al; o2[r]*=al; o3[r]*=al;
      int row = quad*4+r;
      unsigned short hi,lo;
      splitbf(p0,hi,lo); PWh[w][row][   qm]=hi; PWl[w][row][   qm]=lo;
      splitbf(p1,hi,lo); PWh[w][row][16+qm]=hi; PWl[w][row][16+qm]=lo;
      splitbf(p2,hi,lo); PWh[w][row][32+qm]=hi; PWl[w][row][32+qm]=lo;
      splitbf(p3,hi,lo); PWh[w][row][48+qm]=hi; PWl[w][row][48+qm]=lo;
    }
    __builtin_amdgcn_wave_barrier();   // order ds_writes before ds_reads (per-wave)
    short8 ph0 = *(const short8*)(&PWh[w][qm][quad*8]);
    short8 ph1 = *(const short8*)(&PWh[w][qm][32+quad*8]);
    short8 pl0 = *(const short8*)(&PWl[w][qm][quad*8]);
    short8 pl1 = *(const short8*)(&PWl[w][qm][32+quad*8]);
    __builtin_amdgcn_wave_barrier();   // order reads before next iter's writes
    {
      const unsigned short* vr0h = vbase_h + ((long)(0*16+qm))*SEQ + kt;
      const unsigned short* vr1h = vbase_h + ((long)(1*16+qm))*SEQ + kt;
      const unsigned short* vr2h = vbase_h + ((long)(2*16+qm))*SEQ + kt;
      const unsigned short* vr3h = vbase_h + ((long)(3*16+qm))*SEQ + kt;
      const unsigned short* vr0l = vbase_l + ((long)(0*16+qm))*SEQ + kt;
      const unsigned short* vr1l = vbase_l + ((long)(1*16+qm))*SEQ + kt;
      const unsigned short* vr2l = vbase_l + ((long)(2*16+qm))*SEQ + kt;
      const unsigned short* vr3l = vbase_l + ((long)(3*16+qm))*SEQ + kt;
      short8 v0h0=*(const short8*)(vr0h+quad*8), v0h1=*(const short8*)(vr0h+32+quad*8);
      short8 v1h0=*(const short8*)(vr1h+quad*8), v1h1=*(const short8*)(vr1h+32+quad*8);
      short8 v2h0=*(const short8*)(vr2h+quad*8), v2h1=*(const short8*)(vr2h+32+quad*8);
      short8 v3h0=*(const short8*)(vr3h+quad*8), v3h1=*(const short8*)(vr3h+32+quad*8);
      short8 v0l0=*(const short8*)(vr0l+quad*8), v0l1=*(const short8*)(vr0l+32+quad*8);
      short8 v1l0=*(const short8*)(vr1l+quad*8), v1l1=*(const short8*)(vr1l+32+quad*8);
      short8 v2l0=*(const short8*)(vr2l+quad*8), v2l1=*(const short8*)(vr2l+32+quad*8);
      short8 v3l0=*(const short8*)(vr3l+quad*8), v3l1=*(const short8*)(vr3l+32+quad*8);
      o0 = __builtin_amdgcn_mfma_f32_16x16x32_bf16(ph0,v0h0,o0,0,0,0);
      o0 = __builtin_amdgcn_mfma_f32_16x16x32_bf16(ph1,v0h1,o0,0,0,0);
      o0 = __builtin_amdgcn_mfma_f32_16x16x32_bf16(ph0,v0l0,o0,0,0,0);
      o0 = __builtin_amdgcn_mfma_f32_16x16x32_bf16(ph1,v0l1,o0,0,0,0);
      o0 = __builtin_amdgcn_mfma_f32_16x16x32_bf16(pl0,v0h0,o0,0,0,0);
      o0 = __builtin_amdgcn_mfma_f32_16x16x32_bf16(pl1,v0h1,o0,0,0,0);
      o1 = __builtin_amdgcn_mfma_f32_16x16x32_bf16(ph0,v1h0,o1,0,0,0);
      o1 = __builtin_amdgcn_mfma_f32_16x16x32_bf16(ph1,v1h1,o1,0,0,0);
      o1 = __builtin_amdgcn_mfma_f32_16x16x32_bf16(ph0,v1l0,o1,0,0,0);
      o1 = __builtin_amdgcn_mfma_f32_16x16x32_bf16(ph1,v1l1,o1,0,0,0);
      o1 = __builtin_amdgcn_mfma_f32_16x16x32_bf16(pl0,v1h0,o1,0,0,0);
      o1 = __builtin_amdgcn_mfma_f32_16x16x32_bf16(pl1,v1h1,o1,0,0,0);
      o2 = __builtin_amdgcn_mfma_f32_16x16x32_bf16(ph0,v2h0,o2,0,0,0);
      o2 = __builtin_amdgcn_mfma_f32_16x16x32_bf16(ph1,v2h1,o2,0,0,0);
      o2 = __builtin_amdgcn_mfma_f32_16x16x32_bf16(ph0,v2l0,o2,0,0,0);
      o2 = __builtin_amdgcn_mfma_f32_16x16x32_bf16(ph1,v2l1,o2,0,0,0);
      o2 = __builtin_amdgcn_mfma_f32_16x16x32_bf16(pl0,v2h0,o2,0,0,0);
      o2 = __builtin_amdgcn_mfma_f32_16x16x32_bf16(pl1,v2h1,o2,0,0,0);
      o3 = __builtin_amdgcn_mfma_f32_16x16x32_bf16(ph0,v3h0,o3,0,0,0);
      o3 = __builtin_amdgcn_mfma_f32_16x16x32_bf16(ph1,v3h1,o3,0,0,0);
      o3 = __builtin_amdgcn_mfma_f32_16x16x32_bf16(ph0,v3l0,o3,0,0,0);
      o3 = __builtin_amdgcn_mfma_f32_16x16x32_bf16(ph1,v3l1,o3,0,0,0);
      o3 = __builtin_amdgcn_mfma_f32_16x16x32_bf16(pl0,v3h0,o3,0,0,0);
      o3 = __builtin_amdgcn_mfma_f32_16x16x32_bf16(pl1,v3h1,o3,0,0,0);
    }
  }
  #pragma unroll
  for(int r=0;r<4;r++){
    float inv = 1.f/l[r];
    long rb = ((long)(b*SEQ + q0 + quad*4 + r))*DMODEL + h*DK;
    unsigned short hi,lo;
    splitbf(o0[r]*inv,hi,lo); dmh[rb+   qm]=hi; dml[rb+   qm]=lo;
    splitbf(o1[r]*inv,hi,lo); dmh[rb+16+qm]=hi; dml[rb+16+qm]=lo;
    splitbf(o2[r]*inv,hi,lo); dmh[rb+32+qm]=hi; dml[rb+32+qm]=lo;
    splitbf(o3[r]*inv,hi,lo); dmh[rb+48+qm]=hi; dml[rb+48+qm]=lo;
  }
}

// ---- delta: context & ksum per (b,h), fp32 from split inputs ---------------
__global__ __launch_bounds__(256) void k_delta_ctx(
    const unsigned short* __restrict__ qh, const unsigned short* __restrict__ qlp,
    float* __restrict__ ctx, float* __restrict__ ksum){
  int bh = blockIdx.x, b=bh>>4, h=bh&15;
  __shared__ unsigned short kdh[64][64], kdl[64][64], vdh[64][64], vdl[64][64];
  int tid = threadIdx.x;
  int i = tid>>2, jg = (tid&3)*16;
  float acc[16]; for(int k=0;k<16;k++) acc[k]=0.f;
  float ks = 0.f;
  int rr = tid>>2, cg = (tid&3)*16;
  for(int s0=0;s0<SEQ;s0+=64){
    __syncthreads();
    long base = (long)(b*SEQ + s0 + rr)*6144 + h*DK;
    *(short8*)(&kdh[rr][cg])   = *(const short8*)(qh  + base + 4096 + cg);
    *(short8*)(&kdh[rr][cg+8]) = *(const short8*)(qh  + base + 4096 + cg + 8);
    *(short8*)(&kdl[rr][cg])   = *(const short8*)(qlp + base + 4096 + cg);
    *(short8*)(&kdl[rr][cg+8]) = *(const short8*)(qlp + base + 4096 + cg + 8);
    *(short8*)(&vdh[rr][cg])   = *(const short8*)(qh  + base + 5120 + cg);
    *(short8*)(&vdh[rr][cg+8]) = *(const short8*)(qh  + base + 5120 + cg + 8);
    *(short8*)(&vdl[rr][cg])   = *(const short8*)(qlp + base + 5120 + cg);
    *(short8*)(&vdl[rr][cg+8]) = *(const short8*)(qlp + base + 5120 + cg + 8);
    __syncthreads();
    for(int s=0;s<64;s++){
      float kv = bf2f(kdh[s][i]) + bf2f(kdl[s][i]);
      if((tid&3)==0) ks += fmaxf(kv,0.f);
      for(int j=0;j<16;j++)
        acc[j] += kv * (bf2f(vdh[s][jg+j]) + bf2f(vdl[s][jg+j]));
    }
  }
  long cb = (long)bh*DK*DK;
  for(int j=0;j<16;j++) ctx[cb + (long)i*DK + jg + j] = acc[j];
  if((tid&3)==0) ksum[bh*DK + i] = ks;
}

// ---- delta: out = relu(qd)@ctx / z, split-bf16 output ----------------------
__global__ __launch_bounds__(256) void k_delta_out(
    const unsigned short* __restrict__ qh, const unsigned short* __restrict__ qlp,
    const float* __restrict__ ctx, const float* __restrict__ ksum,
    unsigned short* __restrict__ dlh, unsigned short* __restrict__ dll){
  int tok = blockIdx.x, b = tok>>10;
  int tid = threadIdx.x;
  __shared__ float ql[DMODEL];
  long sb = (long)tok*6144 + 3072;
  for(int c=tid;c<DMODEL;c+=256)
    ql[c] = fmaxf(bf2f(qh[sb+c]) + bf2f(qlp[sb+c]), 0.f);
  __syncthreads();
  int h = tid>>4, dg = (tid&15)*4;
  int bh = b*NHEAD + h;
  const float* C = ctx + (long)bh*DK*DK;
  const float* KS = ksum + bh*DK;
  float a0=0,a1=0,a2=0,a3=0,z=0;
  for(int d=0;d<DK;d++){
    float q = ql[h*DK + d];
    z += q * KS[d];
    const float* cr = C + d*DK + dg;
    a0 += q*cr[0]; a1 += q*cr[1]; a2 += q*cr[2]; a3 += q*cr[3];
  }
  float inv = 1.f/(z + 1e-6f);
  long db = (long)tok*DMODEL + h*DK + dg;
  unsigned short hi,lo;
  splitbf(a0*inv,hi,lo); dlh[db  ]=hi; dll[db  ]=lo;
  splitbf(a1*inv,hi,lo); dlh[db+1]=hi; dll[db+1]=lo;
  splitbf(a2*inv,hi,lo); dlh[db+2]=hi; dll[db+2]=lo;
  splitbf(a3*inv,hi,lo); dlh[db+3]=hi; dll[db+3]=lo;
}

// ---- fused: x1 = x+g0*dp+g1*dlp (fp32); h2=LN2(x1); router top2 ------------
__global__ __launch_bounds__(256) void k_comb_router(
    const float* __restrict__ x, const float* __restrict__ dp,
    const float* __restrict__ dlp, const float* __restrict__ gates,
    const float* __restrict__ g, const float* __restrict__ bb,
    const float* __restrict__ wr, unsigned short* __restrict__ h2b,
    float* __restrict__ topw, int* __restrict__ topi, int* __restrict__ counts){
  __shared__ float red[4];
  __shared__ float ered[4][8];
  int t = blockIdx.x, tid = threadIdx.x;
  float g0 = gates[t*2], g1 = gates[t*2+1];
  long base = (long)t*DMODEL + tid*4;
  floatx4 xv = *(const floatx4*)(x + base);
  float v[4];
  for(int i=0;i<4;i++) v[i] = xv[i] + g0*dp[base+i] + g1*dlp[base+i];
  float s = block_sum(v[0]+v[1]+v[2]+v[3], red);
  float mu = s*(1.f/DMODEL);
  float q=0.f; for(int i=0;i<4;i++){ float d=v[i]-mu; q+=d*d; }
  q = block_sum(q, red);
  float inv = rsqrtf(q*(1.f/DMODEL)+1e-5f);
  float a[8]; for(int e=0;e<8;e++) a[e]=0.f;
  for(int i=0;i<4;i++){
    int d = tid*4+i;
    float hv = (v[i]-mu)*inv*g[d] + bb[d];
    h2b[base+i] = f2bf(hv);
    const float* wrow = wr + (long)d*NEXP;
    for(int e=0;e<8;e++) a[e] += hv*wrow[e];
  }
  for(int off=32;off;off>>=1)
    for(int e=0;e<8;e++) a[e] += __shfl_down(a[e],off,64);
  int w = tid>>6;
  if((tid&63)==0) for(int e=0;e<8;e++) ered[w][e]=a[e];
  __syncthreads();
  if(tid==0){
    float lg[8];
    for(int e=0;e<8;e++) lg[e]=ered[0][e]+ered[1][e]+ered[2][e]+ered[3][e];
    int i0=0; for(int e=1;e<8;e++) if(lg[e]>lg[i0]) i0=e;
    int i1=-1; for(int e=0;e<8;e++){ if(e==i0) continue; if(i1<0||lg[e]>lg[i1]) i1=e; }
    float mm=fmaxf(lg[i0],lg[i1]), e0=__expf(lg[i0]-mm), e1=__expf(lg[i1]-mm), s2=1.f/(e0+e1);
    topw[t*2]=e0*s2; topw[t*2+1]=e1*s2;
    topi[t*2]=i0; topi[t*2+1]=i1;
    atomicAdd(&counts[i0],1); atomicAdd(&counts[i1],1);
  }
}

// ---- expert segment offsets + tile table -----------------------------------
__global__ void k_meta(const int* __restrict__ counts, int* offs, int* tE,
                       int* tR0, int* tR1, int* ntp, int* cursor){
  if(threadIdx.x==0){
    int o=0, nt=0;
    for(int e=0;e<NEXP;e++){
      offs[e]=o; cursor[e]=0;
      int n=counts[e];
      for(int t=0;t<(n+63)/64;t++){ tE[nt]=e; tR0[nt]=o+t*64; tR1[nt]=o+n; nt++; }
      o+=n;
    }
    offs[NEXP]=o; ntp[0]=nt;
  }
}

// ---- scatter tokens into expert-sorted slots -------------------------------
__global__ __launch_bounds__(256) void k_scatter(
    const int* __restrict__ topi, const int* __restrict__ offs,
    int* cursor, int* perm, int* slotof){
  int token = blockIdx.x*256 + threadIdx.x;
  for(int k=0;k<2;k++){
    int e = topi[token*2+k];
    int pos = atomicAdd(&cursor[e],1);
    int slot = offs[e]+pos;
    perm[slot]=token; slotof[token*2+k]=slot;
  }
}

// ---- MoE GEMM 1: H = gelu(gather(h2b) @ e_w1[e]) ---------------------------
__global__ __launch_bounds__(256) void k_moe1(
    const unsigned short* __restrict__ A, const unsigned short* __restrict__ BtA,
    unsigned short* __restrict__ H, const int* __restrict__ perm,
    const int* __restrict__ ntp, const int* __restrict__ tE,
    const int* __restrict__ tR0, const int* __restrict__ tR1){
  int bz = blockIdx.y;
  if(bz >= ntp[0]) return;
  int e = tE[bz], r0t = tR0[bz], r1t = tR1[bz];
  __shared__ int toks[64];
  __shared__ unsigned short As[64][40], Bs[64][40];
  int tid = threadIdx.x;
  if(tid<64){ int gg=r0t+tid; toks[tid] = (gg<r1t)? perm[gg] : -1; }
  __syncthreads();
  const unsigned short* Bt = BtA + (long)e*DFF*DMODEL;
  int n0 = blockIdx.x*64;
  int w=tid>>6, lane=tid&63, qm=lane&15, quad=lane>>4;
  int sr=tid>>2, sc=(tid&3)*8;
  int tok = toks[sr];
  floatx4 acc0={0,0,0,0},acc1={0,0,0,0},acc2={0,0,0,0},acc3={0,0,0,0};
  const short8 z8 = {0,0,0,0,0,0,0,0};
  const unsigned short* Bp = Bt + (long)(n0+sr)*DMODEL + sc;
  for(int k0=0;k0<DMODEL;k0+=32){
    short8 av = (tok>=0) ? *(const short8*)(A + (long)tok*DMODEL + k0 + sc) : z8;
    short8 bv = *(const short8*)(Bp + k0);
    __syncthreads();
    *(short8*)(&As[sr][sc]) = av;
    *(short8*)(&Bs[sr][sc]) = bv;
    __syncthreads();
    short8 a  = *(const short8*)(&As[w*16+qm][quad*8]);
    short8 b0 = *(const short8*)(&Bs[     qm][quad*8]);
    short8 b1 = *(const short8*)(&Bs[16 + qm][quad*8]);
    short8 b2 = *(const short8*)(&Bs[32 + qm][quad*8]);
    short8 b3 = *(const short8*)(&Bs[48 + qm][quad*8]);
    acc0 = __builtin_amdgcn_mfma_f32_16x16x32_bf16(a,b0,acc0,0,0,0);
    acc1 = __builtin_amdgcn_mfma_f32_16x16x32_bf16(a,b1,acc1,0,0,0);
    acc2 = __builtin_amdgcn_mfma_f32_16x16x32_bf16(a,b2,acc2,0,0,0);
    acc3 = __builtin_amdgcn_mfma_f32_16x16x32_bf16(a,b3,acc3,0,0,0);
  }
  for(int r=0;r<4;r++){
    int gr = r0t + w*16 + quad*4 + r;
    if(gr < r1t){
      long rb = (long)gr*DFF + n0;
      float xx;
      xx=acc0[r]; H[rb+     qm]=f2bf(0.5f*xx*(1.f+erff(xx*0.70710678f)));
      xx=acc1[r]; H[rb+16 + qm]=f2bf(0.5f*xx*(1.f+erff(xx*0.70710678f)));
      xx=acc2[r]; H[rb+32 + qm]=f2bf(0.5f*xx*(1.f+erff(xx*0.70710678f)));
      xx=acc3[r]; H[rb+48 + qm]=f2bf(0.5f*xx*(1.f+erff(xx*0.70710678f)));
    }
  }
}

// ---- MoE GEMM 2: Y = H @ e_w2[e] -------------------------------------------
__global__ __launch_bounds__(256) void k_moe2(
    const unsigned short* __restrict__ H, const unsigned short* __restrict__ BtA,
    unsigned short* __restrict__ Y, const int* __restrict__ ntp,
    const int* __restrict__ tE, const int* __restrict__ tR0,
    const int* __restrict__ tR1){
  int bz = blockIdx.y;
  if(bz >= ntp[0]) return;
  int e = tE[bz], r0t = tR0[bz], r1t = tR1[bz];
  __shared__ unsigned short As[64][40], Bs[64][40];
  int tid = threadIdx.x;
  const unsigned short* Bt = BtA + (long)e*DMODEL*DFF;
  int n0 = blockIdx.x*64;
  int w=tid>>6, lane=tid&63, qm=lane&15, quad=lane>>4;
  int sr=tid>>2, sc=(tid&3)*8;
  int grow = r0t + sr;
  bool vrow = grow < r1t;
  floatx4 acc0={0,0,0,0},acc1={0,0,0,0},acc2={0,0,0,0},acc3={0,0,0,0};
  const short8 z8 = {0,0,0,0,0,0,0,0};
  const unsigned short* Ap = H + (long)grow*DFF + sc;
  const unsigned short* Bp = Bt + (long)(n0+sr)*DFF + sc;
  for(int k0=0;k0<DFF;k0+=32){
    short8 av = vrow ? *(const short8*)(Ap + k0) : z8;
    short8 bv = *(const short8*)(Bp + k0);
    __syncthreads();
    *(short8*)(&As[sr][sc]) = av;
    *(short8*)(&Bs[sr][sc]) = bv;
    __syncthreads();
    short8 a  = *(const short8*)(&As[w*16+qm][quad*8]);
    short8 b0 = *(const short8*)(&Bs[     qm][quad*8]);
    short8 b1 = *(const short8*)(&Bs[16 + qm][quad*8]);
    short8 b2 = *(const short8*)(&Bs[32 + qm][quad*8]);
    short8 b3 = *(const short8*)(&Bs[48 + qm][quad*8]);
    acc0 = __builtin_amdgcn_mfma_f32_16x16x32_bf16(a,b0,acc0,0,0,0);
    acc1 = __builtin_amdgcn_mfma_f32_16x16x32_bf16(a,b1,acc1,0,0,0);
    acc2 = __builtin_amdgcn_mfma_f32_16x16x32_bf16(a,b2,acc2,0,0,0);
    acc3 = __builtin_amdgcn_mfma_f32_16x16x32_bf16(a,b3,acc3,0,0,0);
  }
  for(int r=0;r<4;r++){
    int gr = r0t + w*16 + quad*4 + r;
    if(gr < r1t){
      long rb = (long)gr*DMODEL + n0;
      Y[rb+     qm]=f2bf(acc0[r]);
      Y[rb+16 + qm]=f2bf(acc1[r]);
      Y[rb+32 + qm]=f2bf(acc2[r]);
      Y[rb+48 + qm]=f2bf(acc3[r]);
    }
  }
}

// ---- final: out = x + g0*dp + g1*dlp + w0*Y[s0] + w1*Y[s1] (fp32) ----------
__global__ __launch_bounds__(256) void k_final(
    const float* __restrict__ x, const float* __restrict__ dp,
    const float* __restrict__ dlp, const float* __restrict__ gates,
    const unsigned short* __restrict__ Y, const int* __restrict__ slotof,
    const float* __restrict__ topw, float* __restrict__ out){
  int t = blockIdx.x, tid = threadIdx.x;
  int s0 = slotof[t*2], s1 = slotof[t*2+1];
  float w0 = topw[t*2], w1 = topw[t*2+1];
  float g0 = gates[t*2], g1 = gates[t*2+1];
  long base = (long)t*DMODEL + tid*4;
  const unsigned short* y0 = Y + (long)s0*DMODEL + tid*4;
  const unsigned short* y1 = Y + (long)s1*DMODEL + tid*4;
  floatx4 xv = *(const floatx4*)(x + base);
  for(int i=0;i<4;i++)
    out[base+i] = xv[i] + g0*dp[base+i] + g1*dlp[base+i]
                        + w0*bf2f(y0[i]) + w1*bf2f(y1[i]);
}

// ===========================================================================
extern "C" void kernel_launch(void* const* d_in, const int* in_sizes, int n_in,
                              void* d_out, int out_size, void* d_ws, size_t ws_size,
                              hipStream_t stream){
  const float* x    = (const float*)d_in[0];
  const int*   mask = (const int*)d_in[1];
  const float* ln1g = (const float*)d_in[2];
  const float* ln1b = (const float*)d_in[3];
  const float* wq   = (const float*)d_in[4];
  const float* wk   = (const float*)d_in[5];
  const float* wv   = (const float*)d_in[6];
  const float* wo   = (const float*)d_in[7];
  const float* wqd  = (const float*)d_in[8];
  const float* wkd  = (const float*)d_in[9];
  const float* wvd  = (const float*)d_in[10];
  const float* wod  = (const float*)d_in[11];
  const float* wg   = (const float*)d_in[12];
  const float* ln2g = (const float*)d_in[13];
  const float* ln2b = (const float*)d_in[14];
  const float* wr   = (const float*)d_in[15];
  const float* ew1  = (const float*)d_in[16];
  const float* ew2  = (const float*)d_in[17];
  float* out = (float*)d_out;

  char* p = (char*)d_ws;
  auto alloc = [&](size_t b)->char*{ char* r=p; p += (b + 255) & ~(size_t)255; return r; };
  unsigned short* WtAllh = (unsigned short*)alloc(6144L*1024*2);
  unsigned short* WtAlll = (unsigned short*)alloc(6144L*1024*2);
  unsigned short* WoTh   = (unsigned short*)alloc(1024L*1024*2);
  unsigned short* WoTl   = (unsigned short*)alloc(1024L*1024*2);
  unsigned short* WodTh  = (unsigned short*)alloc(1024L*1024*2);
  unsigned short* WodTl  = (unsigned short*)alloc(1024L*1024*2);
  unsigned short* eW1T   = (unsigned short*)alloc(8L*2048*1024*2);
  unsigned short* eW2T   = (unsigned short*)alloc(8L*1024*2048*2);
  unsigned short* h1h    = (unsigned short*)alloc(4096L*1024*2);  // later vTh
  unsigned short* h1l    = (unsigned short*)alloc(4096L*1024*2);  // later vTl
  unsigned short* qkvh   = (unsigned short*)alloc(4096L*6144*2);  // later dproj+dlproj (fp32)
  unsigned short* qkvl   = (unsigned short*)alloc(4096L*6144*2);  // later H
  unsigned short* dmh    = (unsigned short*)alloc(4096L*1024*2);  // later Y (dmh..dml)
  unsigned short* dml    = (unsigned short*)alloc(4096L*1024*2);
  unsigned short* dlh    = (unsigned short*)alloc(4096L*1024*2);
  unsigned short* dll    = (unsigned short*)alloc(4096L*1024*2);
  float* ctx   = (float*)alloc(64L*64*64*4);
  float* ksum  = (float*)alloc(64L*64*4);
  float* gates = (float*)alloc(4096L*2*4);
  unsigned short* h2b = (unsigned short*)alloc(4096L*1024*2);
  float* topw = (float*)alloc(4096L*2*4);
  int* topi   = (int*)alloc(4096L*2*4);
  int* slotof = (int*)alloc(4096L*2*4);
  int* perm   = (int*)alloc(8192L*4);
  int* counts = (int*)alloc(64*4);
  int* cursor = (int*)alloc(64*4);
  int* offs   = (int*)alloc(64*4);
  int* ntp    = (int*)alloc(64*4);
  int* tE     = (int*)alloc(MAXTILE*4);
  int* tR0    = (int*)alloc(MAXTILE*4);
  int* tR1    = (int*)alloc(MAXTILE*4);
  unsigned long long* mpack = (unsigned long long*)alloc(4L*1024*16*8);
  if ((size_t)(p - (char*)d_ws) > ws_size) return;  // ws too small -> absmax==ref max

  unsigned short* vTh = h1h;                    // after h1 consumed (qkv gemm + gate)
  unsigned short* vTl = h1l;
  float* dproj  = (float*)qkvh;                 // after qkv consumed (attn+delta)
  float* dlproj = (float*)(qkvh + 8388608);     // second 16.8MB of qkvh region
  unsigned short* H = qkvl;                     // after qkv consumed
  unsigned short* Y = dmh;                      // spans dmh+dml (16.8MB)

  dim3 tb(256);
  // mask bit-pack (independent)
  k_maskpack<<<16384,tb,0,stream>>>(mask, mpack);
  // weight transposes: attention weights split, MoE weights single bf16
  k_transpose_f2<<<dim3(32,32,1),tb,0,stream>>>(wq,  WtAllh+0L*1048576, WtAlll+0L*1048576, 1024,1024, 0,0);
  k_transpose_f2<<<dim3(32,32,1),tb,0,stream>>>(wk,  WtAllh+1L*1048576, WtAlll+1L*1048576, 1024,1024, 0,0);
  k_transpose_f2<<<dim3(32,32,1),tb,0,stream>>>(wv,  WtAllh+2L*1048576, WtAlll+2L*1048576, 1024,1024, 0,0);
  k_transpose_f2<<<dim3(32,32,1),tb,0,stream>>>(wqd, WtAllh+3L*1048576, WtAlll+3L*1048576, 1024,1024, 0,0);
  k_transpose_f2<<<dim3(32,32,1),tb,0,stream>>>(wkd, WtAllh+4L*1048576, WtAlll+4L*1048576, 1024,1024, 0,0);
  k_transpose_f2<<<dim3(32,32,1),tb,0,stream>>>(wvd, WtAllh+5L*1048576, WtAlll+5L*1048576, 1024,1024, 0,0);
  k_transpose_f2<<<dim3(32,32,1),tb,0,stream>>>(wo,  WoTh,  WoTl,  1024,1024, 0,0);
  k_transpose_f2<<<dim3(32,32,1),tb,0,stream>>>(wod, WodTh, WodTl, 1024,1024, 0,0);
  k_transpose_f<<<dim3(64,32,8),tb,0,stream>>>(ew1, eW1T, 2048,1024, 1024L*2048, 2048L*1024);
  k_transpose_f<<<dim3(32,64,8),tb,0,stream>>>(ew2, eW2T, 1024,2048, 2048L*1024, 1024L*2048);
  // LN1 -> h1 split
  k_ln1<<<4096,tb,0,stream>>>(x, ln1g, ln1b, h1h, h1l);
  // qkv: all 6 projections, split in/out
  k_gemm_ss<1><<<dim3(96,64),tb,0,stream>>>(h1h,h1l, WtAllh,WtAlll, qkvh,qkvl,nullptr,
                                            1024, 1024, 1024, 6144);
  // gate (fp32 path)
  k_gate<<<1024,tb,0,stream>>>(h1h, h1l, wg, gates);
  // vT planes (one launch)
  k_vt<<<dim3(32,2,64),tb,0,stream>>>(qkvh, qkvl, vTh, vTl);
  // flash attention v2 (split precision)
  k_attn_flash2<<<dim3(16,64),tb,0,stream>>>(qkvh, qkvl, vTh, vTl, mpack, dmh, dml);
  // delta branch
  k_delta_ctx<<<64,tb,0,stream>>>(qkvh, qkvl, ctx, ksum);
  k_delta_out<<<4096,tb,0,stream>>>(qkvh, qkvl, ctx, ksum, dlh, dll);
  // output projections -> fp32
  k_gemm_ss<0><<<dim3(16,64),tb,0,stream>>>(dmh,dml, WoTh,WoTl,  nullptr,nullptr,dproj,
                                            1024, 1024, 1024, 1024);
  k_gemm_ss<0><<<dim3(16,64),tb,0,stream>>>(dlh,dll, WodTh,WodTl, nullptr,nullptr,dlproj,
                                            1024, 1024, 1024, 1024);
  // residual + gate-mix + LN2 + router (all fp32)
  hipMemsetAsync(counts, 0, NEXP*sizeof(int), stream);
  k_comb_router<<<4096,tb,0,stream>>>(x, dproj, dlproj, gates, ln2g, ln2b, wr,
                                      h2b, topw, topi, counts);
  k_meta<<<1,64,0,stream>>>(counts, offs, tE, tR0, tR1, ntp, cursor);
  k_scatter<<<16,tb,0,stream>>>(topi, offs, cursor, perm, slotof);
  // expert GEMMs
  k_moe1<<<dim3(32,136),tb,0,stream>>>(h2b, eW1T, H, perm, ntp, tE, tR0, tR1);
  k_moe2<<<dim3(16,136),tb,0,stream>>>(H, eW2T, Y, ntp, tE, tR0, tR1);
  // final residual combine
  k_final<<<4096,tb,0,stream>>>(x, dproj, dlproj, gates, Y, slotof, topw, out);
}